// Round 9
// baseline (675.218 us; speedup 1.0000x reference)
//
#include <hip/hip_runtime.h>
#include <hip/hip_bf16.h>
#include <math.h>

using bf16 = __hip_bfloat16;
using bf16x8 = __attribute__((ext_vector_type(8))) short;
using f32x4 = __attribute__((ext_vector_type(4))) float;

#define D_MODEL 1024
#define N_HEADS 16
#define D_K 64
#define D_FF 4096
#define BATCH 4
#define SEQ 2048
#define M_TOT (BATCH*SEQ)   // 8192

__device__ __forceinline__ void async_copy16(void* lds, const void* g) {
    __builtin_amdgcn_global_load_lds((const __attribute__((address_space(1))) void*)g,
                                     (__attribute__((address_space(3))) void*)lds, 16, 0, 0);
}

// GELU with branch-free A&S 7.1.26 erf (|eps| <= 1.5e-7 absolute).
// [R7: never reg-cap kernels with big AGPR accumulators - unified file spills]
// [R8: sched_barrier(0) per r-iter keeps VGPR at 76, occupancy 29%]
__device__ __forceinline__ float gelu_fast(float v) {
    float x  = v * 0.70710678118654752f;
    float ax = __builtin_fabsf(x);
    float t  = __builtin_amdgcn_rcpf(__builtin_fmaf(0.3275911f, ax, 1.0f));
    float p  = __builtin_fmaf(t, 1.061405429f, -1.453152027f);
    p = __builtin_fmaf(t, p, 1.421413741f);
    p = __builtin_fmaf(t, p, -0.284496736f);
    p = __builtin_fmaf(t, p, 0.254829592f);
    p *= t;
    float e = __builtin_expf(-ax * ax);
    float erf_abs = __builtin_fmaf(-p, e, 1.0f);
    float erfv = __builtin_copysignf(erf_abs, x);
    return 0.5f * v * (1.0f + erfv);
}

// ---------------- single-launch fp32->bf16 convert for 7 segments ----------------
__global__ void __launch_bounds__(256) cvt7_kernel(
    const float* __restrict__ s0, bf16* __restrict__ d0, int n0,
    const float* __restrict__ s1, bf16* __restrict__ d1, int n1,
    const float* __restrict__ s2, bf16* __restrict__ d2, int n2,
    const float* __restrict__ s3, bf16* __restrict__ d3, int n3,
    const float* __restrict__ s4, bf16* __restrict__ d4, int n4,
    const float* __restrict__ s5, bf16* __restrict__ d5, int n5,
    const float* __restrict__ s6, bf16* __restrict__ d6, int n6) {
    int e0 = n0, e1 = e0 + n1, e2 = e1 + n2, e3 = e2 + n3, e4 = e3 + n4, e5 = e4 + n5, e6 = e5 + n6;
    int stride = gridDim.x * blockDim.x;
    for (int i = blockIdx.x * blockDim.x + threadIdx.x; i < e6; i += stride) {
        const float* s; bf16* d; int j;
        if      (i < e0) { s = s0; d = d0; j = i; }
        else if (i < e1) { s = s1; d = d1; j = i - e0; }
        else if (i < e2) { s = s2; d = d2; j = i - e1; }
        else if (i < e3) { s = s3; d = d3; j = i - e2; }
        else if (i < e4) { s = s4; d = d4; j = i - e3; }
        else if (i < e5) { s = s5; d = d5; j = i - e4; }
        else             { s = s6; d = d6; j = i - e5; }
        float4 v = *(const float4*)&s[(size_t)j * 4];
        union { bf16 h[4]; short4 sh; } u;
        u.h[0] = __float2bfloat16(v.x);
        u.h[1] = __float2bfloat16(v.y);
        u.h[2] = __float2bfloat16(v.z);
        u.h[3] = __float2bfloat16(v.w);
        *(short4*)&d[(size_t)j * 4] = u.sh;
    }
}

// ---------------- BK=64 staging + 2x16-MFMA sub-steps (shared macro body) ------
// [R9: halves barrier/drain count vs BK=32; 32KB LDS keeps 3 blocks/CU (reg-bound);
//  sched_barrier(0) between halves caps fragment live ranges]
#define GEMM_K_LOOP(KLIM) \
    for (int k0 = 0; k0 < (KLIM); k0 += 64) {                                        \
        __syncthreads();                                                             \
        _Pragma("unroll")                                                            \
        for (int p = 0; p < 4; p++) {                                                \
            int c = p * 256 + tid;                                                   \
            int row = c >> 3;                                                        \
            int col = (c & 7) << 3;                                                  \
            async_copy16(&As[c * 8], Ag + (size_t)row * K + k0 + col);               \
        }                                                                            \
        _Pragma("unroll")                                                            \
        for (int p = 0; p < 4; p++) {                                                \
            int c = p * 256 + tid;                                                   \
            int row = c >> 3;                                                        \
            int col = (c & 7) << 3;                                                  \
            async_copy16(&Bs[c * 8], Bg + (size_t)row * K + k0 + col);               \
        }                                                                            \
        __syncthreads();                                                             \
        _Pragma("unroll")                                                            \
        for (int kk = 0; kk < 2; kk++) {                                             \
            bf16x8 a[4], b[4];                                                       \
            _Pragma("unroll")                                                        \
            for (int i = 0; i < 4; i++)                                              \
                a[i] = *(const bf16x8*)&As[(wr + i * 16 + l16) * 64 + kk * 32 + quad * 8]; \
            _Pragma("unroll")                                                        \
            for (int j = 0; j < 4; j++)                                              \
                b[j] = *(const bf16x8*)&Bs[(wc + j * 16 + l16) * 64 + kk * 32 + quad * 8]; \
            _Pragma("unroll")                                                        \
            for (int i = 0; i < 4; i++)                                              \
                _Pragma("unroll")                                                    \
                for (int j = 0; j < 4; j++)                                          \
                    acc[i][j] = __builtin_amdgcn_mfma_f32_16x16x32_bf16(a[i], b[j], acc[i][j], 0, 0, 0); \
            __builtin_amdgcn_sched_barrier(0);                                       \
        }                                                                            \
    }

// ---------------- GEMM: C[M,N] = A[M,K] * B[N,K]^T + bias, fused epilogues ----
// EPI 0: bf16 store (bias)
// EPI 1: fp32 store bias+residual
// EPI 3: bf16 store bias, cols<1024 prescaled by 0.125*log2(e)  (QKV: Q-scale fold)
template<int EPI>
__global__ void __launch_bounds__(256) gemm_bt(const bf16* __restrict__ A,
                                               const bf16* __restrict__ B,
                                               const float* __restrict__ bias,
                                               const float* __restrict__ resid,
                                               float* __restrict__ Cf,
                                               bf16* __restrict__ Cb,
                                               int M, int N, int K) {
    __shared__ __align__(16) bf16 As[128 * 64];
    __shared__ __align__(16) bf16 Bs[128 * 64];
    const int tid  = threadIdx.x;
    const int lane = tid & 63;
    const int wave = tid >> 6;
    const int quad = lane >> 4;
    const int l16  = lane & 15;
    const int wr   = (wave >> 1) * 64;
    const int wc   = (wave & 1) * 64;
    const int m0   = blockIdx.y * 128;
    const int n0   = blockIdx.x * 128;

    const bf16* Ag = A + (size_t)m0 * K;
    const bf16* Bg = B + (size_t)n0 * K;

    f32x4 acc[4][4] = {};

    GEMM_K_LOOP(K)

#pragma unroll
    for (int i = 0; i < 4; i++) {
#pragma unroll
        for (int r = 0; r < 4; r++) {
            int row = m0 + wr + i * 16 + quad * 4 + r;
            size_t rb = (size_t)row * N;
#pragma unroll
            for (int j = 0; j < 4; j++) {
                int col = n0 + wc + j * 16 + l16;
                float v = acc[i][j][r] + bias[col];
                if (EPI == 0) {
                    Cb[rb + col] = __float2bfloat16(v);
                } else if (EPI == 1) {
                    Cf[rb + col] = v + resid[rb + col];
                } else {
                    float sc = (col < 1024) ? 0.18033688011112043f : 1.0f;
                    Cb[rb + col] = __float2bfloat16(v * sc);
                }
            }
        }
    }
}

// ---------------- GELU GEMM (FF1) ----------------
__global__ void __launch_bounds__(256) gemm_bt_gelu(const bf16* __restrict__ A,
                                                    const bf16* __restrict__ B,
                                                    const float* __restrict__ bias,
                                                    bf16* __restrict__ Cb,
                                                    int M, int N, int K) {
    __shared__ __align__(16) bf16 As[128 * 64];
    __shared__ __align__(16) bf16 Bs[128 * 64];
    const int tid  = threadIdx.x;
    const int lane = tid & 63;
    const int wave = tid >> 6;
    const int quad = lane >> 4;
    const int l16  = lane & 15;
    const int wr   = (wave >> 1) * 64;
    const int wc   = (wave & 1) * 64;
    const int m0   = blockIdx.y * 128;
    const int n0   = blockIdx.x * 128;

    const bf16* Ag = A + (size_t)m0 * K;
    const bf16* Bg = B + (size_t)n0 * K;

    f32x4 acc[4][4] = {};

    GEMM_K_LOOP(K)

#pragma unroll
    for (int i = 0; i < 4; i++) {
#pragma unroll
        for (int r = 0; r < 4; r++) {
            int row = m0 + wr + i * 16 + quad * 4 + r;
            size_t rb = (size_t)row * N;
#pragma unroll
            for (int j = 0; j < 4; j++) {
                int col = n0 + wc + j * 16 + l16;
                float v = acc[i][j][r] + bias[col];
                Cb[rb + col] = __float2bfloat16(gelu_fast(v));
            }
            // cap live GELU temps at 4 (R6: uncapped -> VGPR 88, occupancy loss)
            __builtin_amdgcn_sched_barrier(0);
        }
    }
}

// ---------------- split-K GEMM: P[z] = A[:, z*KS:(z+1)*KS] * B^T (raw fp32) ----
__global__ void __launch_bounds__(256) gemm_bt_sk(const bf16* __restrict__ A,
                                                  const bf16* __restrict__ B,
                                                  float* __restrict__ P,
                                                  int M, int N, int K, int KS) {
    __shared__ __align__(16) bf16 As[128 * 64];
    __shared__ __align__(16) bf16 Bs[128 * 64];
    const int tid  = threadIdx.x;
    const int lane = tid & 63;
    const int wave = tid >> 6;
    const int quad = lane >> 4;
    const int l16  = lane & 15;
    const int wr   = (wave >> 1) * 64;
    const int wc   = (wave & 1) * 64;
    const int m0   = blockIdx.y * 128;
    const int n0   = blockIdx.x * 128;
    const int kbeg = blockIdx.z * KS;

    const bf16* Ag = A + (size_t)m0 * K + kbeg;
    const bf16* Bg = B + (size_t)n0 * K + kbeg;
    float* Pz = P + (size_t)blockIdx.z * M * N;

    f32x4 acc[4][4] = {};

    GEMM_K_LOOP(KS)

#pragma unroll
    for (int i = 0; i < 4; i++) {
#pragma unroll
        for (int r = 0; r < 4; r++) {
            int row = m0 + wr + i * 16 + quad * 4 + r;
            size_t rb = (size_t)row * N;
#pragma unroll
            for (int j = 0; j < 4; j++) {
                int col = n0 + wc + j * 16 + l16;
                Pz[rb + col] = acc[i][j][r];
            }
        }
    }
}

// ---------------- flash attention (causal), v3 ----------------
__global__ void __launch_bounds__(256) attn_kernel(const bf16* __restrict__ qkv,
                                                   bf16* __restrict__ ctx) {
    const int pair = blockIdx.x;          // 0..7
    const int h    = blockIdx.y;
    const int bb   = blockIdx.z;
    const int tid  = threadIdx.x;
    const int lane = tid & 63;
    const int wave = tid >> 6;
    const int quad = lane >> 4;
    const int l16  = lane & 15;

    __shared__ __align__(16) bf16 Pool[4 * 32 * 80];   // 20480 B
    __shared__ __align__(16) bf16 Ks[2][64 * 64];      // 2 x 8192 B
    __shared__ __align__(16) bf16 Vt[2][64 * 80];      // 2 x 10240 B  [d][k]

    const size_t rowbase = (size_t)(bb * SEQ) * 3072;
    bf16* Pw = &Pool[wave * 32 * 80];
    const int swkey = (l16 >> 2) & 3;

#pragma unroll 1
    for (int phase = 0; phase < 2; phase++) {
        const int qb = (phase == 0) ? pair : (15 - pair);
        const int q0 = qb * 128;
        const int nkb = 2 * (qb + 1);

        __syncthreads();

#pragma unroll
        for (int p = 0; p < 4; p++) {
            int c = p * 256 + tid;
            int row = c >> 3;
            int off = (c & 7) * 8;
            async_copy16(&Pool[c * 8], qkv + rowbase + (size_t)(q0 + row) * 3072 + h * 64 + off);
        }
#pragma unroll
        for (int p = 0; p < 2; p++) {
            int c = p * 256 + tid;
            async_copy16(&Ks[0][c * 8],
                         qkv + rowbase + (size_t)(c >> 3) * 3072 + 1024 + h * 64 + (c & 7) * 8);
        }
        const int vk  = tid & 63;
        const int vd0a = (tid >> 6) * 8;
        const int vd0b = vd0a + 32;
        bf16x8 vr0 = *(const bf16x8*)&qkv[rowbase + (size_t)vk * 3072 + 2048 + h * 64 + vd0a];
        bf16x8 vr1 = *(const bf16x8*)&qkv[rowbase + (size_t)vk * 3072 + 2048 + h * 64 + vd0b];

        __syncthreads();

        bf16x8 aq[2][2];
#pragma unroll
        for (int i = 0; i < 2; i++)
#pragma unroll
            for (int kd = 0; kd < 2; kd++)
                aq[i][kd] = *(const bf16x8*)&Pool[(wave * 32 + i * 16 + l16) * 64 + kd * 32 + quad * 8];

#pragma unroll
        for (int u = 0; u < 8; u++) {
            Vt[0][(vd0a + u) * 80 + vk] = ((const bf16*)&vr0)[u];
            Vt[0][(vd0b + u) * 80 + vk] = ((const bf16*)&vr1)[u];
        }

        f32x4 o[2][4] = {};
        float l_acc[2][4] = {};

#pragma unroll 1
        for (int kb = 0; kb < nkb; kb++) {
            const int cur = kb & 1;
            const int nxt = cur ^ 1;
            __syncthreads();

            const bool pf = (kb + 1 < nkb);
            bf16x8 nv0, nv1;
            if (pf) {
#pragma unroll
                for (int p = 0; p < 2; p++) {
                    int c = p * 256 + tid;
                    async_copy16(&Ks[nxt][c * 8],
                                 qkv + rowbase + (size_t)((kb + 1) * 64 + (c >> 3)) * 3072 + 1024 + h * 64 + (c & 7) * 8);
                }
                nv0 = *(const bf16x8*)&qkv[rowbase + (size_t)((kb + 1) * 64 + vk) * 3072 + 2048 + h * 64 + vd0a];
                nv1 = *(const bf16x8*)&qkv[rowbase + (size_t)((kb + 1) * 64 + vk) * 3072 + 2048 + h * 64 + vd0b];
            }

            f32x4 s[2][4] = {};
#pragma unroll
            for (int jb = 0; jb < 4; jb++) {
#pragma unroll
                for (int kd = 0; kd < 2; kd++) {
                    bf16x8 bk = *(const bf16x8*)&Ks[cur][(jb * 16 + l16) * 64 + kd * 32 + quad * 8];
#pragma unroll
                    for (int i = 0; i < 2; i++)
                        s[i][jb] = __builtin_amdgcn_mfma_f32_16x16x32_bf16(aq[i][kd], bk, s[i][jb], 0, 0, 0);
                }
            }

            if (pf) {
#pragma unroll
                for (int u = 0; u < 8; u++) {
                    Vt[nxt][(vd0a + u) * 80 + vk] = ((const bf16*)&nv0)[u];
                    Vt[nxt][(vd0b + u) * 80 + vk] = ((const bf16*)&nv1)[u];
                }
            }

            const bool diagb = (kb >= 2 * qb);
#pragma unroll
            for (int i = 0; i < 2; i++) {
                const int row0 = q0 + wave * 32 + i * 16;
                const bool needmask = diagb && (kb * 64 + 63 > row0);
#pragma unroll
                for (int jb = 0; jb < 4; jb++) {
                    const int colg = kb * 64 + jb * 16 + l16;
                    const int colsw = ((jb ^ quad) * 16) + l16;
#pragma unroll
                    for (int r = 0; r < 4; r++) {
                        float t = s[i][jb][r];
                        if (needmask && colg > row0 + quad * 4 + r) t = -1e30f;
                        float p = exp2f(t);
                        l_acc[i][r] += p;
                        Pw[(i * 16 + quad * 4 + r) * 80 + colsw] = __float2bfloat16(p);
                    }
                }
            }

#pragma unroll
            for (int kk = 0; kk < 2; kk++) {
                bf16x8 bv[4];
#pragma unroll
                for (int nb = 0; nb < 4; nb++)
                    bv[nb] = *(const bf16x8*)&Vt[cur][(nb * 16 + l16) * 80 + kk * 32 + quad * 8];
                const int grp = kk * 2 + (quad >> 1);
                const int coff = ((grp ^ swkey) * 16) + (quad & 1) * 8;
#pragma unroll
                for (int i = 0; i < 2; i++) {
                    bf16x8 ap = *(const bf16x8*)&Pw[(i * 16 + l16) * 80 + coff];
#pragma unroll
                    for (int nb = 0; nb < 4; nb++)
                        o[i][nb] = __builtin_amdgcn_mfma_f32_16x16x32_bf16(ap, bv[nb], o[i][nb], 0, 0, 0);
                }
            }
        }

#pragma unroll
        for (int i = 0; i < 2; i++)
#pragma unroll
            for (int r = 0; r < 4; r++) {
#pragma unroll
                for (int msk = 1; msk < 16; msk <<= 1)
                    l_acc[i][r] += __shfl_xor(l_acc[i][r], msk, 64);
            }

#pragma unroll
        for (int i = 0; i < 2; i++)
#pragma unroll
            for (int r = 0; r < 4; r++) {
                int rowg = q0 + wave * 32 + i * 16 + quad * 4 + r;
                size_t base = ((size_t)(bb * SEQ + rowg)) * D_MODEL + h * 64;
                float inv = 1.0f / l_acc[i][r];
#pragma unroll
                for (int nb = 0; nb < 4; nb++)
                    ctx[base + nb * 16 + l16] = __float2bfloat16(o[i][nb][r] * inv);
            }
    }
}

// ---------------- LayerNorm (row = 1024 fp32) ----------------
__global__ void __launch_bounds__(256) ln_kernel(const float* __restrict__ in,
                                                 const float* __restrict__ sc,
                                                 const float* __restrict__ bi,
                                                 float* __restrict__ of,
                                                 bf16* __restrict__ ob) {
    int row = blockIdx.x;
    const float* rp = in + (size_t)row * D_MODEL;
    int t = threadIdx.x;
    float4 v = *(const float4*)&rp[t * 4];
    float s1 = v.x + v.y + v.z + v.w;
    float s2 = v.x * v.x + v.y * v.y + v.z * v.z + v.w * v.w;
#pragma unroll
    for (int m = 32; m > 0; m >>= 1) {
        s1 += __shfl_xor(s1, m, 64);
        s2 += __shfl_xor(s2, m, 64);
    }
    __shared__ float red[8];
    int wave = t >> 6, lane = t & 63;
    if (lane == 0) { red[wave] = s1; red[wave + 4] = s2; }
    __syncthreads();
    float S1 = red[0] + red[1] + red[2] + red[3];
    float S2 = red[4] + red[5] + red[6] + red[7];
    float mu = S1 * (1.0f / 1024.0f);
    float var = S2 * (1.0f / 1024.0f) - mu * mu;
    float rstd = rsqrtf(var + 1e-5f);
    float4 g = *(const float4*)&sc[t * 4];
    float4 b = *(const float4*)&bi[t * 4];
    float o0 = (v.x - mu) * rstd * g.x + b.x;
    float o1 = (v.y - mu) * rstd * g.y + b.y;
    float o2 = (v.z - mu) * rstd * g.z + b.z;
    float o3 = (v.w - mu) * rstd * g.w + b.w;
    size_t base = (size_t)row * D_MODEL + t * 4;
    if (of) {
        float4 ov; ov.x = o0; ov.y = o1; ov.z = o2; ov.w = o3;
        *(float4*)&of[base] = ov;
    }
    if (ob) {
        union { bf16 h[4]; short4 s; } u;
        u.h[0] = __float2bfloat16(o0);
        u.h[1] = __float2bfloat16(o1);
        u.h[2] = __float2bfloat16(o2);
        u.h[3] = __float2bfloat16(o3);
        *(short4*)&ob[base] = u.s;
    }
}

// ---------------- fused split-K reduce + bias + residual + LayerNorm -> out ----
__global__ void __launch_bounds__(256) ln2_reduce_kernel(const float* __restrict__ p0,
                                                         const float* __restrict__ p1,
                                                         const float* __restrict__ bias,
                                                         const float* __restrict__ resid,
                                                         const float* __restrict__ sc,
                                                         const float* __restrict__ bi,
                                                         float* __restrict__ out) {
    int row = blockIdx.x;
    int t = threadIdx.x;
    size_t base = (size_t)row * D_MODEL + t * 4;
    float4 a = *(const float4*)&p0[base];
    float4 b4 = *(const float4*)&p1[base];
    float4 rr = *(const float4*)&resid[base];
    float4 bb = *(const float4*)&bias[t * 4];
    float v0 = a.x + b4.x + bb.x + rr.x;
    float v1 = a.y + b4.y + bb.y + rr.y;
    float v2 = a.z + b4.z + bb.z + rr.z;
    float v3 = a.w + b4.w + bb.w + rr.w;
    float s1 = v0 + v1 + v2 + v3;
    float s2 = v0 * v0 + v1 * v1 + v2 * v2 + v3 * v3;
#pragma unroll
    for (int m = 32; m > 0; m >>= 1) {
        s1 += __shfl_xor(s1, m, 64);
        s2 += __shfl_xor(s2, m, 64);
    }
    __shared__ float red[8];
    int wave = t >> 6, lane = t & 63;
    if (lane == 0) { red[wave] = s1; red[wave + 4] = s2; }
    __syncthreads();
    float S1 = red[0] + red[1] + red[2] + red[3];
    float S2 = red[4] + red[5] + red[6] + red[7];
    float mu = S1 * (1.0f / 1024.0f);
    float var = S2 * (1.0f / 1024.0f) - mu * mu;
    float rstd = rsqrtf(var + 1e-5f);
    float4 g = *(const float4*)&sc[t * 4];
    float4 bv = *(const float4*)&bi[t * 4];
    float4 ov;
    ov.x = (v0 - mu) * rstd * g.x + bv.x;
    ov.y = (v1 - mu) * rstd * g.y + bv.y;
    ov.z = (v2 - mu) * rstd * g.z + bv.z;
    ov.w = (v3 - mu) * rstd * g.w + bv.w;
    *(float4*)&out[base] = ov;
}

// ---------------- workspace layout (bytes) ----------------
static const size_t OFF_WQKV = 0;
static const size_t OFF_WO   = 6291456;
static const size_t OFF_W1   = 8388608;
static const size_t OFF_W2   = 16777216;
static const size_t OFF_BQKV = 25165824;
static const size_t OFF_XB   = 25178112;
static const size_t OFF_QKV  = 41955328;
static const size_t OFF_CTX  = 92286976;
static const size_t OFF_HF   = 109064192;
static const size_t OFF_HB   = 142618624;
static const size_t OFF_FF   = 159395840;
static const size_t OFF_RES1 = OFF_QKV;     // fp32 [8192,1024] (qkv dead after attn)
static const size_t OFF_P0   = OFF_QKV;                 // 33554432 B
static const size_t OFF_P1   = OFF_QKV + 33554432;      // ends exactly at OFF_HF

extern "C" void kernel_launch(void* const* d_in, const int* in_sizes, int n_in,
                              void* d_out, int out_size, void* d_ws, size_t ws_size,
                              hipStream_t stream) {
    const float* x     = (const float*)d_in[0];
    const float* wq    = (const float*)d_in[2];
    const float* bq    = (const float*)d_in[3];
    const float* wk    = (const float*)d_in[4];
    const float* bk    = (const float*)d_in[5];
    const float* wv    = (const float*)d_in[6];
    const float* bv    = (const float*)d_in[7];
    const float* wo    = (const float*)d_in[8];
    const float* bo    = (const float*)d_in[9];
    const float* w1    = (const float*)d_in[10];
    const float* b1    = (const float*)d_in[11];
    const float* w2    = (const float*)d_in[12];
    const float* b2    = (const float*)d_in[13];
    const float* ln1_s = (const float*)d_in[14];
    const float* ln1_b = (const float*)d_in[15];
    const float* ln2_s = (const float*)d_in[16];
    const float* ln2_b = (const float*)d_in[17];

    char* ws = (char*)d_ws;
    bf16* wqkv_b = (bf16*)(ws + OFF_WQKV);
    bf16* wo_b   = (bf16*)(ws + OFF_WO);
    bf16* w1_b   = (bf16*)(ws + OFF_W1);
    bf16* w2_b   = (bf16*)(ws + OFF_W2);
    float* bqkv  = (float*)(ws + OFF_BQKV);
    bf16* x_b    = (bf16*)(ws + OFF_XB);
    bf16* qkv    = (bf16*)(ws + OFF_QKV);
    bf16* ctx    = (bf16*)(ws + OFF_CTX);
    float* h_f   = (float*)(ws + OFF_HF);
    bf16* h_b    = (bf16*)(ws + OFF_HB);
    bf16* ff     = (bf16*)(ws + OFF_FF);
    float* res1  = (float*)(ws + OFF_RES1);
    float* p0    = (float*)(ws + OFF_P0);
    float* p1    = (float*)(ws + OFF_P1);

    // --- all fp32->bf16 converts in ONE launch (weights + x) ---
    cvt7_kernel<<<2560, 256, 0, stream>>>(
        wq, wqkv_b,                 262144,
        wk, wqkv_b + 1024 * 1024,   262144,
        wv, wqkv_b + 2 * 1024 * 1024, 262144,
        wo, wo_b,                   262144,
        w1, w1_b,                   1048576,
        w2, w2_b,                   1048576,
        x,  x_b,                    2097152);
    hipMemcpyAsync(bqkv,        bq, 1024 * sizeof(float), hipMemcpyDeviceToDevice, stream);
    hipMemcpyAsync(bqkv + 1024, bk, 1024 * sizeof(float), hipMemcpyDeviceToDevice, stream);
    hipMemcpyAsync(bqkv + 2048, bv, 1024 * sizeof(float), hipMemcpyDeviceToDevice, stream);

    // --- QKV projection (Q prescaled by 0.125*log2e) ---
    gemm_bt<3><<<dim3(3072 / 128, M_TOT / 128), 256, 0, stream>>>(
        x_b, wqkv_b, bqkv, nullptr, nullptr, qkv, M_TOT, 3072, 1024);

    // --- attention (pair-balanced) ---
    attn_kernel<<<dim3(8, N_HEADS, BATCH), 256, 0, stream>>>(qkv, ctx);

    // --- out proj + residual(x): res1 fp32 ---
    gemm_bt<1><<<dim3(1024 / 128, M_TOT / 128), 256, 0, stream>>>(
        ctx, wo_b, bo, x, res1, nullptr, M_TOT, 1024, 1024);

    // --- LN1 -> h (fp32 + bf16) ---
    ln_kernel<<<M_TOT, 256, 0, stream>>>(res1, ln1_s, ln1_b, h_f, h_b);

    // --- FF1 + GELU (fast erf, epilogue serialized) ---
    gemm_bt_gelu<<<dim3(4096 / 128, M_TOT / 128), 256, 0, stream>>>(
        h_b, w1_b, b1, ff, M_TOT, 4096, 1024);

    // --- FF2 split-K=2: partials p0,p1 (1024 blocks -> 4/CU) ---
    gemm_bt_sk<<<dim3(1024 / 128, M_TOT / 128, 2), 256, 0, stream>>>(
        ff, w2_b, p0, M_TOT, 1024, 4096, 2048);

    // --- fused reduce + bias + residual(h) + LN2 -> d_out ---
    ln2_reduce_kernel<<<M_TOT, 256, 0, stream>>>(p0, p1, b2, h_f, ln2_s, ln2_b, (float*)d_out);
}

// Round 10
// 625.169 us; speedup vs baseline: 1.0801x; 1.0801x over previous
//
#include <hip/hip_runtime.h>
#include <hip/hip_bf16.h>
#include <math.h>

using bf16 = __hip_bfloat16;
using bf16x8 = __attribute__((ext_vector_type(8))) short;
using f32x4 = __attribute__((ext_vector_type(4))) float;

#define D_MODEL 1024
#define N_HEADS 16
#define D_K 64
#define D_FF 4096
#define BATCH 4
#define SEQ 2048
#define M_TOT (BATCH*SEQ)   // 8192

__device__ __forceinline__ void async_copy16(void* lds, const void* g) {
    __builtin_amdgcn_global_load_lds((const __attribute__((address_space(1))) void*)g,
                                     (__attribute__((address_space(3))) void*)lds, 16, 0, 0);
}

// GELU with branch-free A&S 7.1.26 erf (|eps| <= 1.5e-7 absolute).
// [R7: never reg-cap kernels with big AGPR accumulators - unified file spills]
// [R8: sched_barrier(0) per r-iter keeps VGPR at 76, occupancy 29%]
__device__ __forceinline__ float gelu_fast(float v) {
    float x  = v * 0.70710678118654752f;
    float ax = __builtin_fabsf(x);
    float t  = __builtin_amdgcn_rcpf(__builtin_fmaf(0.3275911f, ax, 1.0f));
    float p  = __builtin_fmaf(t, 1.061405429f, -1.453152027f);
    p = __builtin_fmaf(t, p, 1.421413741f);
    p = __builtin_fmaf(t, p, -0.284496736f);
    p = __builtin_fmaf(t, p, 0.254829592f);
    p *= t;
    float e = __builtin_expf(-ax * ax);
    float erf_abs = __builtin_fmaf(-p, e, 1.0f);
    float erfv = __builtin_copysignf(erf_abs, x);
    return 0.5f * v * (1.0f + erfv);
}

// ---------------- single-launch fp32->bf16 convert for 7 segments ----------------
__global__ void __launch_bounds__(256) cvt7_kernel(
    const float* __restrict__ s0, bf16* __restrict__ d0, int n0,
    const float* __restrict__ s1, bf16* __restrict__ d1, int n1,
    const float* __restrict__ s2, bf16* __restrict__ d2, int n2,
    const float* __restrict__ s3, bf16* __restrict__ d3, int n3,
    const float* __restrict__ s4, bf16* __restrict__ d4, int n4,
    const float* __restrict__ s5, bf16* __restrict__ d5, int n5,
    const float* __restrict__ s6, bf16* __restrict__ d6, int n6) {
    int e0 = n0, e1 = e0 + n1, e2 = e1 + n2, e3 = e2 + n3, e4 = e3 + n4, e5 = e4 + n5, e6 = e5 + n6;
    int stride = gridDim.x * blockDim.x;
    for (int i = blockIdx.x * blockDim.x + threadIdx.x; i < e6; i += stride) {
        const float* s; bf16* d; int j;
        if      (i < e0) { s = s0; d = d0; j = i; }
        else if (i < e1) { s = s1; d = d1; j = i - e0; }
        else if (i < e2) { s = s2; d = d2; j = i - e1; }
        else if (i < e3) { s = s3; d = d3; j = i - e2; }
        else if (i < e4) { s = s4; d = d4; j = i - e3; }
        else if (i < e5) { s = s5; d = d5; j = i - e4; }
        else             { s = s6; d = d6; j = i - e5; }
        float4 v = *(const float4*)&s[(size_t)j * 4];
        union { bf16 h[4]; short4 sh; } u;
        u.h[0] = __float2bfloat16(v.x);
        u.h[1] = __float2bfloat16(v.y);
        u.h[2] = __float2bfloat16(v.z);
        u.h[3] = __float2bfloat16(v.w);
        *(short4*)&d[(size_t)j * 4] = u.sh;
    }
}

// ---------------- BK=32 K-loop with XOR bank swizzle --------------------------
// [R9 lesson: BK=64's 128B row stride = same-bank rows -> 2.5e7 conflicts. Reverted.]
// [R10: BK=32's 64B stride gives 8-way phase conflicts (8.4e6 counter). Fix:
//  swizzle the GLOBAL source k-group (coalescing unchanged - same 64B per row,
//  permuted among 4 threads) so LDS phys slot (row, pg) holds logical group
//  pg ^ ((row>>1)&3). global_load_lds lane-contiguity preserved; reads spread
//  over 8 banks = 2-way = free (m136). All swizzle math is K-loop-invariant.]
#define GEMM_K_LOOP(KLIM) \
    for (int k0 = 0; k0 < (KLIM); k0 += 32) {                                        \
        __syncthreads();                                                             \
        _Pragma("unroll")                                                            \
        for (int p = 0; p < 2; p++) {                                                \
            int c = p * 256 + tid;                                                   \
            int row = c >> 2;                                                        \
            int col = (((c & 3) ^ ((row >> 1) & 3))) << 3;                           \
            async_copy16(&As[c * 8], Ag + (size_t)row * K + k0 + col);               \
            async_copy16(&Bs[c * 8], Bg + (size_t)row * K + k0 + col);               \
        }                                                                            \
        __syncthreads();                                                             \
        bf16x8 a[4], b[4];                                                           \
        _Pragma("unroll")                                                            \
        for (int i = 0; i < 4; i++) {                                                \
            int ra = wr + i * 16 + l16;                                              \
            a[i] = *(const bf16x8*)&As[ra * 32 + ((quad ^ ((ra >> 1) & 3)) << 3)];   \
        }                                                                            \
        _Pragma("unroll")                                                            \
        for (int j = 0; j < 4; j++) {                                                \
            int rb2 = wc + j * 16 + l16;                                             \
            b[j] = *(const bf16x8*)&Bs[rb2 * 32 + ((quad ^ ((rb2 >> 1) & 3)) << 3)]; \
        }                                                                            \
        _Pragma("unroll")                                                            \
        for (int i = 0; i < 4; i++)                                                  \
            _Pragma("unroll")                                                        \
            for (int j = 0; j < 4; j++)                                              \
                acc[i][j] = __builtin_amdgcn_mfma_f32_16x16x32_bf16(a[i], b[j], acc[i][j], 0, 0, 0); \
    }

// ---------------- GEMM: C[M,N] = A[M,K] * B[N,K]^T + bias, fused epilogues ----
// EPI 0: bf16 store (bias)
// EPI 1: fp32 store bias+residual
// EPI 3: bf16 store bias, cols<1024 prescaled by 0.125*log2(e)  (QKV: Q-scale fold)
template<int EPI>
__global__ void __launch_bounds__(256) gemm_bt(const bf16* __restrict__ A,
                                               const bf16* __restrict__ B,
                                               const float* __restrict__ bias,
                                               const float* __restrict__ resid,
                                               float* __restrict__ Cf,
                                               bf16* __restrict__ Cb,
                                               int M, int N, int K) {
    __shared__ __align__(16) bf16 As[128 * 32];
    __shared__ __align__(16) bf16 Bs[128 * 32];
    const int tid  = threadIdx.x;
    const int lane = tid & 63;
    const int wave = tid >> 6;
    const int quad = lane >> 4;
    const int l16  = lane & 15;
    const int wr   = (wave >> 1) * 64;
    const int wc   = (wave & 1) * 64;
    const int m0   = blockIdx.y * 128;
    const int n0   = blockIdx.x * 128;

    const bf16* Ag = A + (size_t)m0 * K;
    const bf16* Bg = B + (size_t)n0 * K;

    f32x4 acc[4][4] = {};

    GEMM_K_LOOP(K)

#pragma unroll
    for (int i = 0; i < 4; i++) {
#pragma unroll
        for (int r = 0; r < 4; r++) {
            int row = m0 + wr + i * 16 + quad * 4 + r;
            size_t rb = (size_t)row * N;
#pragma unroll
            for (int j = 0; j < 4; j++) {
                int col = n0 + wc + j * 16 + l16;
                float v = acc[i][j][r] + bias[col];
                if (EPI == 0) {
                    Cb[rb + col] = __float2bfloat16(v);
                } else if (EPI == 1) {
                    Cf[rb + col] = v + resid[rb + col];
                } else {
                    float sc = (col < 1024) ? 0.18033688011112043f : 1.0f;
                    Cb[rb + col] = __float2bfloat16(v * sc);
                }
            }
        }
    }
}

// ---------------- GELU GEMM (FF1) ----------------
__global__ void __launch_bounds__(256) gemm_bt_gelu(const bf16* __restrict__ A,
                                                    const bf16* __restrict__ B,
                                                    const float* __restrict__ bias,
                                                    bf16* __restrict__ Cb,
                                                    int M, int N, int K) {
    __shared__ __align__(16) bf16 As[128 * 32];
    __shared__ __align__(16) bf16 Bs[128 * 32];
    const int tid  = threadIdx.x;
    const int lane = tid & 63;
    const int wave = tid >> 6;
    const int quad = lane >> 4;
    const int l16  = lane & 15;
    const int wr   = (wave >> 1) * 64;
    const int wc   = (wave & 1) * 64;
    const int m0   = blockIdx.y * 128;
    const int n0   = blockIdx.x * 128;

    const bf16* Ag = A + (size_t)m0 * K;
    const bf16* Bg = B + (size_t)n0 * K;

    f32x4 acc[4][4] = {};

    GEMM_K_LOOP(K)

#pragma unroll
    for (int i = 0; i < 4; i++) {
#pragma unroll
        for (int r = 0; r < 4; r++) {
            int row = m0 + wr + i * 16 + quad * 4 + r;
            size_t rb = (size_t)row * N;
#pragma unroll
            for (int j = 0; j < 4; j++) {
                int col = n0 + wc + j * 16 + l16;
                float v = acc[i][j][r] + bias[col];
                Cb[rb + col] = __float2bfloat16(gelu_fast(v));
            }
            // cap live GELU temps at 4 (R6: uncapped -> VGPR 88, occupancy loss)
            __builtin_amdgcn_sched_barrier(0);
        }
    }
}

// ---------------- split-K GEMM: P[z] = A[:, z*KS:(z+1)*KS] * B^T (raw fp32) ----
__global__ void __launch_bounds__(256) gemm_bt_sk(const bf16* __restrict__ A,
                                                  const bf16* __restrict__ B,
                                                  float* __restrict__ P,
                                                  int M, int N, int K, int KS) {
    __shared__ __align__(16) bf16 As[128 * 32];
    __shared__ __align__(16) bf16 Bs[128 * 32];
    const int tid  = threadIdx.x;
    const int lane = tid & 63;
    const int wave = tid >> 6;
    const int quad = lane >> 4;
    const int l16  = lane & 15;
    const int wr   = (wave >> 1) * 64;
    const int wc   = (wave & 1) * 64;
    const int m0   = blockIdx.y * 128;
    const int n0   = blockIdx.x * 128;
    const int kbeg = blockIdx.z * KS;

    const bf16* Ag = A + (size_t)m0 * K + kbeg;
    const bf16* Bg = B + (size_t)n0 * K + kbeg;
    float* Pz = P + (size_t)blockIdx.z * M * N;

    f32x4 acc[4][4] = {};

    GEMM_K_LOOP(KS)

#pragma unroll
    for (int i = 0; i < 4; i++) {
#pragma unroll
        for (int r = 0; r < 4; r++) {
            int row = m0 + wr + i * 16 + quad * 4 + r;
            size_t rb = (size_t)row * N;
#pragma unroll
            for (int j = 0; j < 4; j++) {
                int col = n0 + wc + j * 16 + l16;
                Pz[rb + col] = acc[i][j][r];
            }
        }
    }
}

// ---------------- flash attention (causal), v3 ----------------
__global__ void __launch_bounds__(256) attn_kernel(const bf16* __restrict__ qkv,
                                                   bf16* __restrict__ ctx) {
    const int pair = blockIdx.x;          // 0..7
    const int h    = blockIdx.y;
    const int bb   = blockIdx.z;
    const int tid  = threadIdx.x;
    const int lane = tid & 63;
    const int wave = tid >> 6;
    const int quad = lane >> 4;
    const int l16  = lane & 15;

    __shared__ __align__(16) bf16 Pool[4 * 32 * 80];   // 20480 B
    __shared__ __align__(16) bf16 Ks[2][64 * 64];      // 2 x 8192 B
    __shared__ __align__(16) bf16 Vt[2][64 * 80];      // 2 x 10240 B  [d][k]

    const size_t rowbase = (size_t)(bb * SEQ) * 3072;
    bf16* Pw = &Pool[wave * 32 * 80];
    const int swkey = (l16 >> 2) & 3;

#pragma unroll 1
    for (int phase = 0; phase < 2; phase++) {
        const int qb = (phase == 0) ? pair : (15 - pair);
        const int q0 = qb * 128;
        const int nkb = 2 * (qb + 1);

        __syncthreads();

#pragma unroll
        for (int p = 0; p < 4; p++) {
            int c = p * 256 + tid;
            int row = c >> 3;
            int off = (c & 7) * 8;
            async_copy16(&Pool[c * 8], qkv + rowbase + (size_t)(q0 + row) * 3072 + h * 64 + off);
        }
#pragma unroll
        for (int p = 0; p < 2; p++) {
            int c = p * 256 + tid;
            async_copy16(&Ks[0][c * 8],
                         qkv + rowbase + (size_t)(c >> 3) * 3072 + 1024 + h * 64 + (c & 7) * 8);
        }
        const int vk  = tid & 63;
        const int vd0a = (tid >> 6) * 8;
        const int vd0b = vd0a + 32;
        bf16x8 vr0 = *(const bf16x8*)&qkv[rowbase + (size_t)vk * 3072 + 2048 + h * 64 + vd0a];
        bf16x8 vr1 = *(const bf16x8*)&qkv[rowbase + (size_t)vk * 3072 + 2048 + h * 64 + vd0b];

        __syncthreads();

        bf16x8 aq[2][2];
#pragma unroll
        for (int i = 0; i < 2; i++)
#pragma unroll
            for (int kd = 0; kd < 2; kd++)
                aq[i][kd] = *(const bf16x8*)&Pool[(wave * 32 + i * 16 + l16) * 64 + kd * 32 + quad * 8];

#pragma unroll
        for (int u = 0; u < 8; u++) {
            Vt[0][(vd0a + u) * 80 + vk] = ((const bf16*)&vr0)[u];
            Vt[0][(vd0b + u) * 80 + vk] = ((const bf16*)&vr1)[u];
        }

        f32x4 o[2][4] = {};
        float l_acc[2][4] = {};

#pragma unroll 1
        for (int kb = 0; kb < nkb; kb++) {
            const int cur = kb & 1;
            const int nxt = cur ^ 1;
            __syncthreads();

            const bool pf = (kb + 1 < nkb);
            bf16x8 nv0, nv1;
            if (pf) {
#pragma unroll
                for (int p = 0; p < 2; p++) {
                    int c = p * 256 + tid;
                    async_copy16(&Ks[nxt][c * 8],
                                 qkv + rowbase + (size_t)((kb + 1) * 64 + (c >> 3)) * 3072 + 1024 + h * 64 + (c & 7) * 8);
                }
                nv0 = *(const bf16x8*)&qkv[rowbase + (size_t)((kb + 1) * 64 + vk) * 3072 + 2048 + h * 64 + vd0a];
                nv1 = *(const bf16x8*)&qkv[rowbase + (size_t)((kb + 1) * 64 + vk) * 3072 + 2048 + h * 64 + vd0b];
            }

            f32x4 s[2][4] = {};
#pragma unroll
            for (int jb = 0; jb < 4; jb++) {
#pragma unroll
                for (int kd = 0; kd < 2; kd++) {
                    bf16x8 bk = *(const bf16x8*)&Ks[cur][(jb * 16 + l16) * 64 + kd * 32 + quad * 8];
#pragma unroll
                    for (int i = 0; i < 2; i++)
                        s[i][jb] = __builtin_amdgcn_mfma_f32_16x16x32_bf16(aq[i][kd], bk, s[i][jb], 0, 0, 0);
                }
            }

            if (pf) {
#pragma unroll
                for (int u = 0; u < 8; u++) {
                    Vt[nxt][(vd0a + u) * 80 + vk] = ((const bf16*)&nv0)[u];
                    Vt[nxt][(vd0b + u) * 80 + vk] = ((const bf16*)&nv1)[u];
                }
            }

            const bool diagb = (kb >= 2 * qb);
#pragma unroll
            for (int i = 0; i < 2; i++) {
                const int row0 = q0 + wave * 32 + i * 16;
                const bool needmask = diagb && (kb * 64 + 63 > row0);
#pragma unroll
                for (int jb = 0; jb < 4; jb++) {
                    const int colg = kb * 64 + jb * 16 + l16;
                    const int colsw = ((jb ^ quad) * 16) + l16;
#pragma unroll
                    for (int r = 0; r < 4; r++) {
                        float t = s[i][jb][r];
                        if (needmask && colg > row0 + quad * 4 + r) t = -1e30f;
                        float p = exp2f(t);
                        l_acc[i][r] += p;
                        Pw[(i * 16 + quad * 4 + r) * 80 + colsw] = __float2bfloat16(p);
                    }
                }
            }

#pragma unroll
            for (int kk = 0; kk < 2; kk++) {
                bf16x8 bv[4];
#pragma unroll
                for (int nb = 0; nb < 4; nb++)
                    bv[nb] = *(const bf16x8*)&Vt[cur][(nb * 16 + l16) * 80 + kk * 32 + quad * 8];
                const int grp = kk * 2 + (quad >> 1);
                const int coff = ((grp ^ swkey) * 16) + (quad & 1) * 8;
#pragma unroll
                for (int i = 0; i < 2; i++) {
                    bf16x8 ap = *(const bf16x8*)&Pw[(i * 16 + l16) * 80 + coff];
#pragma unroll
                    for (int nb = 0; nb < 4; nb++)
                        o[i][nb] = __builtin_amdgcn_mfma_f32_16x16x32_bf16(ap, bv[nb], o[i][nb], 0, 0, 0);
                }
            }
        }

#pragma unroll
        for (int i = 0; i < 2; i++)
#pragma unroll
            for (int r = 0; r < 4; r++) {
#pragma unroll
                for (int msk = 1; msk < 16; msk <<= 1)
                    l_acc[i][r] += __shfl_xor(l_acc[i][r], msk, 64);
            }

#pragma unroll
        for (int i = 0; i < 2; i++)
#pragma unroll
            for (int r = 0; r < 4; r++) {
                int rowg = q0 + wave * 32 + i * 16 + quad * 4 + r;
                size_t base = ((size_t)(bb * SEQ + rowg)) * D_MODEL + h * 64;
                float inv = 1.0f / l_acc[i][r];
#pragma unroll
                for (int nb = 0; nb < 4; nb++)
                    ctx[base + nb * 16 + l16] = __float2bfloat16(o[i][nb][r] * inv);
            }
    }
}

// ---------------- LayerNorm (row = 1024 fp32) ----------------
__global__ void __launch_bounds__(256) ln_kernel(const float* __restrict__ in,
                                                 const float* __restrict__ sc,
                                                 const float* __restrict__ bi,
                                                 float* __restrict__ of,
                                                 bf16* __restrict__ ob) {
    int row = blockIdx.x;
    const float* rp = in + (size_t)row * D_MODEL;
    int t = threadIdx.x;
    float4 v = *(const float4*)&rp[t * 4];
    float s1 = v.x + v.y + v.z + v.w;
    float s2 = v.x * v.x + v.y * v.y + v.z * v.z + v.w * v.w;
#pragma unroll
    for (int m = 32; m > 0; m >>= 1) {
        s1 += __shfl_xor(s1, m, 64);
        s2 += __shfl_xor(s2, m, 64);
    }
    __shared__ float red[8];
    int wave = t >> 6, lane = t & 63;
    if (lane == 0) { red[wave] = s1; red[wave + 4] = s2; }
    __syncthreads();
    float S1 = red[0] + red[1] + red[2] + red[3];
    float S2 = red[4] + red[5] + red[6] + red[7];
    float mu = S1 * (1.0f / 1024.0f);
    float var = S2 * (1.0f / 1024.0f) - mu * mu;
    float rstd = rsqrtf(var + 1e-5f);
    float4 g = *(const float4*)&sc[t * 4];
    float4 b = *(const float4*)&bi[t * 4];
    float o0 = (v.x - mu) * rstd * g.x + b.x;
    float o1 = (v.y - mu) * rstd * g.y + b.y;
    float o2 = (v.z - mu) * rstd * g.z + b.z;
    float o3 = (v.w - mu) * rstd * g.w + b.w;
    size_t base = (size_t)row * D_MODEL + t * 4;
    if (of) {
        float4 ov; ov.x = o0; ov.y = o1; ov.z = o2; ov.w = o3;
        *(float4*)&of[base] = ov;
    }
    if (ob) {
        union { bf16 h[4]; short4 s; } u;
        u.h[0] = __float2bfloat16(o0);
        u.h[1] = __float2bfloat16(o1);
        u.h[2] = __float2bfloat16(o2);
        u.h[3] = __float2bfloat16(o3);
        *(short4*)&ob[base] = u.s;
    }
}

// ---------------- fused split-K reduce + bias + residual + LayerNorm -> out ----
__global__ void __launch_bounds__(256) ln2_reduce_kernel(const float* __restrict__ p0,
                                                         const float* __restrict__ p1,
                                                         const float* __restrict__ bias,
                                                         const float* __restrict__ resid,
                                                         const float* __restrict__ sc,
                                                         const float* __restrict__ bi,
                                                         float* __restrict__ out) {
    int row = blockIdx.x;
    int t = threadIdx.x;
    size_t base = (size_t)row * D_MODEL + t * 4;
    float4 a = *(const float4*)&p0[base];
    float4 b4 = *(const float4*)&p1[base];
    float4 rr = *(const float4*)&resid[base];
    float4 bb = *(const float4*)&bias[t * 4];
    float v0 = a.x + b4.x + bb.x + rr.x;
    float v1 = a.y + b4.y + bb.y + rr.y;
    float v2 = a.z + b4.z + bb.z + rr.z;
    float v3 = a.w + b4.w + bb.w + rr.w;
    float s1 = v0 + v1 + v2 + v3;
    float s2 = v0 * v0 + v1 * v1 + v2 * v2 + v3 * v3;
#pragma unroll
    for (int m = 32; m > 0; m >>= 1) {
        s1 += __shfl_xor(s1, m, 64);
        s2 += __shfl_xor(s2, m, 64);
    }
    __shared__ float red[8];
    int wave = t >> 6, lane = t & 63;
    if (lane == 0) { red[wave] = s1; red[wave + 4] = s2; }
    __syncthreads();
    float S1 = red[0] + red[1] + red[2] + red[3];
    float S2 = red[4] + red[5] + red[6] + red[7];
    float mu = S1 * (1.0f / 1024.0f);
    float var = S2 * (1.0f / 1024.0f) - mu * mu;
    float rstd = rsqrtf(var + 1e-5f);
    float4 g = *(const float4*)&sc[t * 4];
    float4 bv = *(const float4*)&bi[t * 4];
    float4 ov;
    ov.x = (v0 - mu) * rstd * g.x + bv.x;
    ov.y = (v1 - mu) * rstd * g.y + bv.y;
    ov.z = (v2 - mu) * rstd * g.z + bv.z;
    ov.w = (v3 - mu) * rstd * g.w + bv.w;
    *(float4*)&out[base] = ov;
}

// ---------------- workspace layout (bytes) ----------------
static const size_t OFF_WQKV = 0;
static const size_t OFF_WO   = 6291456;
static const size_t OFF_W1   = 8388608;
static const size_t OFF_W2   = 16777216;
static const size_t OFF_BQKV = 25165824;
static const size_t OFF_XB   = 25178112;
static const size_t OFF_QKV  = 41955328;
static const size_t OFF_CTX  = 92286976;
static const size_t OFF_HF   = 109064192;
static const size_t OFF_HB   = 142618624;
static const size_t OFF_FF   = 159395840;
static const size_t OFF_RES1 = OFF_QKV;     // fp32 [8192,1024] (qkv dead after attn)
static const size_t OFF_P0   = OFF_QKV;                 // 33554432 B
static const size_t OFF_P1   = OFF_QKV + 33554432;      // ends exactly at OFF_HF

extern "C" void kernel_launch(void* const* d_in, const int* in_sizes, int n_in,
                              void* d_out, int out_size, void* d_ws, size_t ws_size,
                              hipStream_t stream) {
    const float* x     = (const float*)d_in[0];
    const float* wq    = (const float*)d_in[2];
    const float* bq    = (const float*)d_in[3];
    const float* wk    = (const float*)d_in[4];
    const float* bk    = (const float*)d_in[5];
    const float* wv    = (const float*)d_in[6];
    const float* bv    = (const float*)d_in[7];
    const float* wo    = (const float*)d_in[8];
    const float* bo    = (const float*)d_in[9];
    const float* w1    = (const float*)d_in[10];
    const float* b1    = (const float*)d_in[11];
    const float* w2    = (const float*)d_in[12];
    const float* b2    = (const float*)d_in[13];
    const float* ln1_s = (const float*)d_in[14];
    const float* ln1_b = (const float*)d_in[15];
    const float* ln2_s = (const float*)d_in[16];
    const float* ln2_b = (const float*)d_in[17];

    char* ws = (char*)d_ws;
    bf16* wqkv_b = (bf16*)(ws + OFF_WQKV);
    bf16* wo_b   = (bf16*)(ws + OFF_WO);
    bf16* w1_b   = (bf16*)(ws + OFF_W1);
    bf16* w2_b   = (bf16*)(ws + OFF_W2);
    float* bqkv  = (float*)(ws + OFF_BQKV);
    bf16* x_b    = (bf16*)(ws + OFF_XB);
    bf16* qkv    = (bf16*)(ws + OFF_QKV);
    bf16* ctx    = (bf16*)(ws + OFF_CTX);
    float* h_f   = (float*)(ws + OFF_HF);
    bf16* h_b    = (bf16*)(ws + OFF_HB);
    bf16* ff     = (bf16*)(ws + OFF_FF);
    float* res1  = (float*)(ws + OFF_RES1);
    float* p0    = (float*)(ws + OFF_P0);
    float* p1    = (float*)(ws + OFF_P1);

    // --- all fp32->bf16 converts in ONE launch (weights + x) ---
    cvt7_kernel<<<2560, 256, 0, stream>>>(
        wq, wqkv_b,                 262144,
        wk, wqkv_b + 1024 * 1024,   262144,
        wv, wqkv_b + 2 * 1024 * 1024, 262144,
        wo, wo_b,                   262144,
        w1, w1_b,                   1048576,
        w2, w2_b,                   1048576,
        x,  x_b,                    2097152);
    hipMemcpyAsync(bqkv,        bq, 1024 * sizeof(float), hipMemcpyDeviceToDevice, stream);
    hipMemcpyAsync(bqkv + 1024, bk, 1024 * sizeof(float), hipMemcpyDeviceToDevice, stream);
    hipMemcpyAsync(bqkv + 2048, bv, 1024 * sizeof(float), hipMemcpyDeviceToDevice, stream);

    // --- QKV projection (Q prescaled by 0.125*log2e) ---
    gemm_bt<3><<<dim3(3072 / 128, M_TOT / 128), 256, 0, stream>>>(
        x_b, wqkv_b, bqkv, nullptr, nullptr, qkv, M_TOT, 3072, 1024);

    // --- attention (pair-balanced) ---
    attn_kernel<<<dim3(8, N_HEADS, BATCH), 256, 0, stream>>>(qkv, ctx);

    // --- out proj + residual(x): res1 fp32 ---
    gemm_bt<1><<<dim3(1024 / 128, M_TOT / 128), 256, 0, stream>>>(
        ctx, wo_b, bo, x, res1, nullptr, M_TOT, 1024, 1024);

    // --- LN1 -> h (fp32 + bf16) ---
    ln_kernel<<<M_TOT, 256, 0, stream>>>(res1, ln1_s, ln1_b, h_f, h_b);

    // --- FF1 + GELU (fast erf, epilogue serialized) ---
    gemm_bt_gelu<<<dim3(4096 / 128, M_TOT / 128), 256, 0, stream>>>(
        h_b, w1_b, b1, ff, M_TOT, 4096, 1024);

    // --- FF2 split-K=2: partials p0,p1 (1024 blocks -> 4/CU) ---
    gemm_bt_sk<<<dim3(1024 / 128, M_TOT / 128, 2), 256, 0, stream>>>(
        ff, w2_b, p0, M_TOT, 1024, 4096, 2048);

    // --- fused reduce + bias + residual(h) + LN2 -> d_out ---
    ln2_reduce_kernel<<<M_TOT, 256, 0, stream>>>(p0, p1, b2, h_f, ln2_s, ln2_b, (float*)d_out);
}